// Round 4
// baseline (209.282 us; speedup 1.0000x reference)
//
#include <hip/hip_runtime.h>

// SparseEmbedding forward: out[n, :] = weight[indices[n], :]
//   weight : [1'000'000, 128] fp32  (512 B per row)
//   indices: [4096, 200] int (flat N = 819'200)
//   out    : [N, 128] fp32
//
// Round 3 -> 4 changes:
//  - grid-stride loop at 4096 blocks (16/CU) instead of 102K one-shot
//    workgroups: amortizes per-WG dispatch overhead.
//  - 32 B per lane (two dwordx4) : 16 lanes per row, half the VMEM
//    instructions and half the index loads, same traffic.
//  - keep NT stores (round-2 win: output is write-once, stay out of L2/L3
//    so duplicate weight rows survive in cache).

typedef float f32x4 __attribute__((ext_vector_type(4)));

constexpr int PAIRS_PER_ROW = 16;   // 16 lanes/row, each owns 2 float4 = 32 B

__global__ __launch_bounds__(256) void sparse_embedding_gather(
    const f32x4* __restrict__ weight,   // [1e6 * 32] f32x4
    const int*   __restrict__ indices,  // [N]
    f32x4*       __restrict__ out,      // [N * 32] f32x4
    int total_pairs)                    // N * 16
{
    const int stride = gridDim.x * 256;
    for (int i = blockIdx.x * 256 + threadIdx.x; i < total_pairs; i += stride) {
        int row  = i >> 4;        // which output row
        int pair = i & 15;        // which 32 B chunk within the row

        long long src = (long long)indices[row] * 32 + pair * 2;
        f32x4 v0 = weight[src];
        f32x4 v1 = weight[src + 1];

        long long dst = (long long)i * 2;
        __builtin_nontemporal_store(v0, &out[dst]);
        __builtin_nontemporal_store(v1, &out[dst + 1]);
    }
}

extern "C" void kernel_launch(void* const* d_in, const int* in_sizes, int n_in,
                              void* d_out, int out_size, void* d_ws, size_t ws_size,
                              hipStream_t stream) {
    const f32x4* weight  = (const f32x4*)d_in[0];
    const int*   indices = (const int*)d_in[1];
    f32x4*       out     = (f32x4*)d_out;

    const int n_rows      = in_sizes[1];              // 819'200
    const int total_pairs = n_rows * PAIRS_PER_ROW;   // 13'107'200

    const int block  = 256;
    const int blocks = 4096;   // 16 per CU; grid-stride covers the rest

    sparse_embedding_gather<<<blocks, block, 0, stream>>>(
        weight, indices, out, total_pairs);
}

// Round 5
// 124.846 us; speedup vs baseline: 1.6763x; 1.6763x over previous
//
#include <hip/hip_runtime.h>

// SparseEmbedding forward: out[n, :] = weight[indices[n], :]
//   weight : [1'000'000, 128] fp32  (512 B per row)
//   indices: [4096, 200] int (flat N = 819'200)
//   out    : [N, 128] fp32
//
// Round 4 -> 5: revert the strided-access mistake. 16 lanes per row,
// each lane does TWO lane-contiguous dwordx4 loads:
//   v0 at row_base + pair        (lanes 0..15 cover bytes [0,256))
//   v1 at row_base + 16 + pair   (lanes 0..15 cover bytes [256,512))
// Every VMEM instruction is fully coalesced; 2 independent loads/thread
// give ILP; index loads halve vs round 3. One-shot grid (no grid-stride
// -- round 4 showed no benefit). NT stores keep the write-once output
// out of L2/L3 so duplicate weight rows stay cached (round-2 win).

typedef float f32x4 __attribute__((ext_vector_type(4)));

constexpr int LANES_PER_ROW = 16;   // each lane owns 2 x 16 B, halves of the row

__global__ __launch_bounds__(256) void sparse_embedding_gather(
    const f32x4* __restrict__ weight,   // [1e6 * 32] f32x4
    const int*   __restrict__ indices,  // [N]
    f32x4*       __restrict__ out,      // [N * 32] f32x4
    int total_pairs)                    // N * 16
{
    int i = blockIdx.x * 256 + threadIdx.x;
    if (i >= total_pairs) return;

    int row  = i >> 4;        // output row
    int pair = i & 15;        // lane slot within the row

    long long base = (long long)indices[row] * 32;
    f32x4 v0 = weight[base + pair];        // contiguous across lanes
    f32x4 v1 = weight[base + 16 + pair];   // contiguous across lanes

    long long dst = (long long)row * 32 + pair;
    __builtin_nontemporal_store(v0, &out[dst]);
    __builtin_nontemporal_store(v1, &out[dst + 16]);
}

extern "C" void kernel_launch(void* const* d_in, const int* in_sizes, int n_in,
                              void* d_out, int out_size, void* d_ws, size_t ws_size,
                              hipStream_t stream) {
    const f32x4* weight  = (const f32x4*)d_in[0];
    const int*   indices = (const int*)d_in[1];
    f32x4*       out     = (f32x4*)d_out;

    const int n_rows      = in_sizes[1];               // 819'200
    const int total_pairs = n_rows * LANES_PER_ROW;    // 13'107'200

    const int block  = 256;
    const int blocks = (total_pairs + block - 1) / block;  // 51'200

    sparse_embedding_gather<<<blocks, block, 0, stream>>>(
        weight, indices, out, total_pairs);
}